// Round 8
// baseline (153.447 us; speedup 1.0000x reference)
//
#include <hip/hip_runtime.h>
#include <hip/hip_bf16.h>
#include <hip/hip_fp16.h>
#include <math.h>

// Problem constants (from reference)
#define B_   64
#define L_   512
#define V_   20000
#define P_   150
#define M_   6
#define KDIM 300
#define NOUT 750          // P_ * (M_-1) used transition scores
#define CWS  752          // padded row stride (16B-aligned float4 rows)
#define NEGF (-1.0e9f)

// f32 fallback GEMM tiling
#define BM 128
#define BN 128
#define BK 16
#define LDP 132

// MFMA path constants
#define KP 320            // K padded: 10 tiles of 32
#define NIT 10            // K-iters
#define NVG 157           // v-groups of 128
#define NJ  6             // n-groups of 128
#define TILE_U4 1024      // uint4 per (group,it) tile: [s 2][q 4][row 128]
#define SA 1024.0f        // emb scale (keeps lo-split out of fp16 subnormals)
#define SB 16384.0f       // diags scale
#define INV24 (5.9604644775390625e-8f)   // 2^-24

// Scan chunking
#define TCHUNK 32
#define NCHUNK (L_ / TCHUNK)   // 16
#define WARM   5
#define CS_STRIDE 160

typedef _Float16 f16x8 __attribute__((ext_vector_type(8)));
typedef float f32x16 __attribute__((ext_vector_type(16)));

__device__ __forceinline__ float logsigf(float x) {
    // matches jax: -softplus(-x) = min(x,0) - log1p(exp(-|x|))
    return fminf(x, 0.f) - log1pf(expf(-fabsf(x)));
}

// fast variant for k1m epilogue: v_exp_f32/v_log_f32, abs err ~6e-8 (flip-safe budget)
__device__ __forceinline__ float logsigf_fast(float x) {
    return fminf(x, 0.f) - __logf(1.f + __expf(-fabsf(x)));
}

// async global->LDS, 16 B per lane; LDS dst = wave-uniform base + lane*16
__device__ __forceinline__ void gload_lds16(const void* gp, void* lp) {
    __builtin_amdgcn_global_load_lds(
        (const __attribute__((address_space(1))) unsigned int*)gp,
        (__attribute__((address_space(3))) unsigned int*)lp, 16, 0, 0);
}

// ---------------- MFMA path ----------------

// P1: emb [300][20000] -> fp16 hi/lo splits in DMA-tiled layout:
// a_t[g 157][it 10][s 2][q 4][row 128] uint4 (one uint4 = 8 k-values of one row).
__global__ __launch_bounds__(256) void p1_split_a(
    const float* __restrict__ emb, uint4* __restrict__ a_t)
{
    __shared__ float T[64][132];
    const int t  = threadIdx.x;
    const int gx = blockIdx.x;           // v-group 0..156
    const int ky = blockIdx.y;           // 0..4 (64 k each)
    const int v0 = gx * 128;
    const int k0 = ky * 64;

    // load phase: 8 passes; pass p, thread t -> row flat>>5, float4-col flat&31
    #pragma unroll
    for (int pass = 0; pass < 8; ++pass) {
        int flat = pass * 256 + t;
        int krow = flat >> 5;            // 0..63
        int c4   = (flat & 31) * 4;      // 0..124
        int kg   = k0 + krow;
        int v    = v0 + c4;
        float4 f = {0.f, 0.f, 0.f, 0.f};
        if (kg < KDIM && v + 3 < V_)     // V_ % 4 == 0: all-or-nothing
            f = *(const float4*)(emb + (size_t)kg * V_ + v);
        *(float4*)&T[krow][c4] = f;
    }
    __syncthreads();

    // split phase: thread -> v-row (t>>1), 32 k (t&1 half = one K-tile)
    const int vv = t >> 1;
    const int kh = (t & 1) * 32;
    const int it = ky * 2 + (kh >> 5);
    const int v  = v0 + vv;
    if (v < V_) {                         // rows >= V_ left as garbage (row-confined)
        union { ushort u[8]; uint4 q; } H[4], Lo[4];
        #pragma unroll
        for (int i = 0; i < 32; ++i) {
            float x = T[kh + i][vv] * SA;
            __half h = __float2half_rn(x);
            float rem = x - __half2float(h);
            H[i >> 3].u[i & 7]  = __half_as_ushort(h);
            Lo[i >> 3].u[i & 7] = __half_as_ushort(__float2half_rn(rem));
        }
        uint4* tile = a_t + ((size_t)gx * NIT + it) * TILE_U4;
        #pragma unroll
        for (int c = 0; c < 4; ++c) {
            tile[      c * 128 + vv] = H[c].q;    // s=0 (hi)
            tile[512 + c * 128 + vv] = Lo[c].q;   // s=1 (lo)
        }
    }
}

// P2: diags (dpm-mapped, scaled) -> b_t[j 6][it 10][s 2][q 4][row 128] uint4, zero-pad
__global__ __launch_bounds__(256) void p2_split_b(
    const float* __restrict__ diags, uint4* __restrict__ b_t)
{
    const int bidx = blockIdx.x;         // j*10 + it
    const int it   = bidx % NIT;
    const int j    = bidx / NIT;
    const int t    = threadIdx.x;
    const int row  = t >> 1;
    const int qh   = (t & 1) * 2;
    const int n    = j * 128 + row;
    const bool nok = (n < NOUT);
    const int pm   = nok ? ((n / 5) * 6 + (n % 5)) : 0;
    uint4* tile = b_t + (size_t)bidx * TILE_U4;
    #pragma unroll
    for (int qq = 0; qq < 2; ++qq) {
        int q = qh + qq;
        union { ushort u[8]; uint4 v; } H, Lo;
        #pragma unroll
        for (int e = 0; e < 8; ++e) {
            int k = it * 32 + q * 8 + e;
            float x = (nok && k < KDIM) ? diags[(size_t)pm * KDIM + k] * SB : 0.f;
            __half h = __float2half_rn(x);
            float rem = x - __half2float(h);
            H.u[e]  = __half_as_ushort(h);
            Lo.u[e] = __half_as_ushort(__float2half_rn(rem));
        }
        tile[      q * 128 + row] = H.v;
        tile[512 + q * 128 + row] = Lo.v;
    }
}

// K1 (MFMA): C = a1@b1 + a1@b2 + a2@b1 (fp16 split-f32), epilogue logsig+max+store.
// Operands pre-tiled in DMA order: each of a wave's 8 global_load_lds instructions
// reads a CONTIGUOUS 1 KB (16 lines, fully coalesced) straight into the LDS slot.
// Wave w stages section w (A-hi, A-lo, B-hi, B-lo). 2-barrier K-loop, 10 iters.
// 1-D grid 960: bid%8 = XCD: the 6 sibling blocks sharing an A-tile land on one XCD.
__global__ __launch_bounds__(256, 3) void k1m_gemm(
    const uint4* __restrict__ a_t, const uint4* __restrict__ b_t,
    const float* __restrict__ bias, const float* __restrict__ wildc,
    float* __restrict__ cw)
{
    const int bid  = blockIdx.x;
    const int xcd  = bid & 7;
    const int slot = bid >> 3;               // 0..119
    const int g    = xcd + 8 * (slot / 6);   // v-group 0..159
    const int j    = slot % 6;               // n-group
    if (g >= NVG) return;

    __shared__ uint4 sm[4 * 512];            // [sec 4][q 4][row 128] = 32 KB
    const int t    = threadIdx.x;
    const int lane = t & 63;
    const int w    = t >> 6;
    const int wr   = w >> 1, wc = w & 1;
    const int v0   = g * 128;
    const int n0   = j * 128;

    // wave w's tiled global section base (contiguous per iter)
    const uint4* gsec = (w < 2)
        ? a_t + (size_t)g * NIT * TILE_U4 + w * 512
        : b_t + (size_t)j * NIT * TILE_U4 + (w - 2) * 512;

    const int fk16 = lane >> 5;
    const int fm   = lane & 31;

    f32x16 acc[2][2];
    #pragma unroll
    for (int i = 0; i < 2; ++i)
        #pragma unroll
        for (int jj = 0; jj < 2; ++jj)
            #pragma unroll
            for (int r = 0; r < 16; ++r) acc[i][jj][r] = 0.f;

    for (int it = 0; it < NIT; ++it) {
        // stage: 8 async DMA, each 64 lanes x 16 B contiguous = 1 KB
        const uint4* gp = gsec + (size_t)it * TILE_U4 + lane;
        #pragma unroll
        for (int i = 0; i < 8; ++i)
            gload_lds16(gp + i * 64, &sm[w * 512 + i * 64 + lane]);
        __syncthreads();                     // drains vmcnt: LDS tile complete

        #pragma unroll
        for (int s = 0; s < 2; ++s) {
            f16x8 A1[2], A2[2], B1[2], B2[2];
            const int q = s * 2 + fk16;
            #pragma unroll
            for (int ri = 0; ri < 2; ++ri) {
                A1[ri] = *(const f16x8*)&sm[(0 * 4 + q) * 128 + wr * 64 + ri * 32 + fm];
                A2[ri] = *(const f16x8*)&sm[(1 * 4 + q) * 128 + wr * 64 + ri * 32 + fm];
            }
            #pragma unroll
            for (int cj = 0; cj < 2; ++cj) {
                B1[cj] = *(const f16x8*)&sm[(2 * 4 + q) * 128 + wc * 64 + cj * 32 + fm];
                B2[cj] = *(const f16x8*)&sm[(3 * 4 + q) * 128 + wc * 64 + cj * 32 + fm];
            }
            #pragma unroll
            for (int ri = 0; ri < 2; ++ri)
                #pragma unroll
                for (int cj = 0; cj < 2; ++cj) {
                    acc[ri][cj] = __builtin_amdgcn_mfma_f32_32x32x16_f16(A1[ri], B1[cj], acc[ri][cj], 0, 0, 0);
                    acc[ri][cj] = __builtin_amdgcn_mfma_f32_32x32x16_f16(A1[ri], B2[cj], acc[ri][cj], 0, 0, 0);
                    acc[ri][cj] = __builtin_amdgcn_mfma_f32_32x32x16_f16(A2[ri], B1[cj], acc[ri][cj], 0, 0, 0);
                }
        }
        __syncthreads();                     // protect LDS before next stage
    }

    // epilogue: C/D layout col=lane&31, row=(r&3)+8*(r>>2)+4*(lane>>5)
    float biasv[2], lwv[2]; int ncol[2]; bool nok[2];
    #pragma unroll
    for (int cj = 0; cj < 2; ++cj) {
        int n = n0 + wc * 64 + cj * 32 + fm;
        ncol[cj] = n;
        nok[cj]  = (n < NOUT);
        int nc = nok[cj] ? n : 0;
        int pm = (nc / 5) * 6 + (nc % 5);
        biasv[cj] = bias[pm];
        lwv[cj]   = logsigf_fast(wildc[nc]);
    }
    #pragma unroll
    for (int ri = 0; ri < 2; ++ri) {
        int vbase = v0 + wr * 64 + ri * 32 + 4 * fk16;
        #pragma unroll
        for (int cj = 0; cj < 2; ++cj) {
            if (!nok[cj]) continue;
            #pragma unroll
            for (int r = 0; r < 16; ++r) {
                int v = vbase + (r & 3) + 8 * (r >> 2);
                if (v < V_) {
                    float val = acc[ri][cj][r] * INV24 + biasv[cj];
                    cw[(size_t)v * CWS + ncol[cj]] = fmaxf(logsigf_fast(val), lwv[cj]);
                }
            }
        }
    }
}

// ---------------- f32 fallback (round-2 kernel) ----------------

__global__ __launch_bounds__(256) void k1_gemm_cw(
    const float* __restrict__ emb,
    const float* __restrict__ diags,
    const float* __restrict__ bias,
    const float* __restrict__ wildc,
    float* __restrict__ cw)
{
    __shared__ float As[BK][LDP];
    __shared__ float Bs[BK][LDP];

    const int tid = threadIdx.x;
    const int v0 = blockIdx.x * BM;
    const int n0 = blockIdx.y * BN;
    const int tx = tid & 15;
    const int ty = tid >> 4;

    float acc[8][8];
    #pragma unroll
    for (int i = 0; i < 8; ++i)
        #pragma unroll
        for (int j = 0; j < 8; ++j) acc[i][j] = 0.f;

    const int a_k = tid >> 4;
    const int a_v = (tid & 15) * 8;
    const int b_n   = tid >> 1;
    const int b_kof = (tid & 1) * 8;

    int  brow;
    bool bval;
    {
        int n = n0 + b_n;
        bval = (n < NOUT);
        brow = bval ? ((n / 5) * 6 + (n % 5)) : 0;
    }

    for (int k0 = 0; k0 < KDIM; k0 += BK) {
        {
            float4 f0 = {0,0,0,0}, f1 = {0,0,0,0};
            int k = k0 + a_k;
            if (k < KDIM) {
                const float* src = emb + (size_t)k * V_ + v0 + a_v;
                if (v0 + a_v + 3 < V_) f0 = *(const float4*)src;
                if (v0 + a_v + 7 < V_) f1 = *(const float4*)(src + 4);
            }
            *(float4*)&As[a_k][a_v]     = f0;
            *(float4*)&As[a_k][a_v + 4] = f1;
        }
        {
            float4 f = {0,0,0,0}, g = {0,0,0,0};
            if (bval) {
                const float* src = diags + (size_t)brow * KDIM + k0 + b_kof;
                if (k0 + b_kof + 3 < KDIM) f = *(const float4*)src;
                if (k0 + b_kof + 7 < KDIM) g = *(const float4*)(src + 4);
            }
            Bs[b_kof + 0][b_n] = f.x;
            Bs[b_kof + 1][b_n] = f.y;
            Bs[b_kof + 2][b_n] = f.z;
            Bs[b_kof + 3][b_n] = f.w;
            Bs[b_kof + 4][b_n] = g.x;
            Bs[b_kof + 5][b_n] = g.y;
            Bs[b_kof + 6][b_n] = g.z;
            Bs[b_kof + 7][b_n] = g.w;
        }
        __syncthreads();
        #pragma unroll
        for (int k = 0; k < BK; ++k) {
            float4 a0 = *(const float4*)&As[k][tx * 4];
            float4 a1 = *(const float4*)&As[k][64 + tx * 4];
            float4 b0 = *(const float4*)&Bs[k][ty * 8];
            float4 b1 = *(const float4*)&Bs[k][ty * 8 + 4];
            float av[8] = {a0.x, a0.y, a0.z, a0.w, a1.x, a1.y, a1.z, a1.w};
            float bv[8] = {b0.x, b0.y, b0.z, b0.w, b1.x, b1.y, b1.z, b1.w};
            #pragma unroll
            for (int i = 0; i < 8; ++i)
                #pragma unroll
                for (int j = 0; j < 8; ++j)
                    acc[i][j] = fmaf(av[i], bv[j], acc[i][j]);
        }
        __syncthreads();
    }

    float biasv[8], lwv[8];
    #pragma unroll
    for (int j = 0; j < 8; ++j) {
        int n  = n0 + ty * 8 + j;
        int nc = (n < NOUT) ? n : 0;
        int pm = (nc / 5) * 6 + (nc % 5);
        biasv[j] = bias[pm];
        lwv[j]   = logsigf(wildc[nc]);
    }
    #pragma unroll
    for (int i = 0; i < 8; ++i) {
        int v = v0 + ((i < 4) ? (tx * 4 + i) : (64 + tx * 4 + (i - 4)));
        if (v >= V_) continue;
        float r[8];
        #pragma unroll
        for (int j = 0; j < 8; ++j)
            r[j] = fmaxf(logsigf(acc[i][j] + biasv[j]), lwv[j]);
        float* dst = cw + (size_t)v * CWS + n0 + ty * 8;
        if (n0 + ty * 8     < NOUT) *(float4*)dst       = make_float4(r[0], r[1], r[2], r[3]);
        if (n0 + ty * 8 + 4 < NOUT) *(float4*)(dst + 4) = make_float4(r[4], r[5], r[6], r[7]);
    }
}

// ---------------- scan (cooperative LDS staging) + finalize ----------------

// K2: chunked scan, cooperative row staging. Old version: thread p issued 5
// divergent scalar loads per token (20 B stride, ~25 lines per wave-instr) ->
// TA address-serialization bound (~2200 divergent VMEM per CU). New version:
// per round, wave w DMAs the full 3 KB row cw[tok] with 3 contiguous
// global_load_lds (16 lines each, TA optimum); threads read 5 values from LDS
// (bank 5p+j, 5 coprime 32 -> conflict-free). 1024 blocks x 3 waves = 10+
// blocks/CU TLP to hide the per-round barrier drain.
__global__ __launch_bounds__(192) void k2_scan(
    const int* __restrict__ docs,
    const int* __restrict__ doc_lens,
    const float* __restrict__ cw,
    float* __restrict__ cs)
{
    const int ci = blockIdx.x;
    const int b  = blockIdx.y;
    const int t0 = ci * TCHUNK;
    const int ts = (t0 >= WARM) ? (t0 - WARM) : 0;
    const int dl = doc_lens[b];
    const int te = min(t0 + TCHUNK, dl);
    const int nt = te - ts;              // tokens to process (may be <= 0)

    __shared__ int   toks[TCHUNK + WARM];
    __shared__ float rows[3][768];       // 3 KB rows (750 used + pad), 9 KB total

    const int t    = threadIdx.x;
    const int lane = t & 63;
    const int w    = t >> 6;             // wave 0..2

    if (t < TCHUNK + WARM) {
        int tt = ts + t;
        toks[t] = docs[b * L_ + min(tt, L_ - 1)];
    }
    __syncthreads();

    const int p      = t;                // pattern if < P_
    const int e      = (p < 50) ? 3 : (p < 100) ? 4 : 5;
    const int warm_n = t0 - ts;
    float h1 = NEGF, h2 = NEGF, h3 = NEGF, h4 = NEGF, h5 = NEGF, sc = NEGF;

    const int nrounds = (nt > 0) ? (nt + 2) / 3 : 0;
    for (int r = 0; r < nrounds; ++r) {
        // wave w stages row for token index 3r+w (clamped; duplicates harmless).
        // 3 DMA instrs x 1 KB cover 3072 B >= 3008 B row (64 B overrun reads the
        // next row / cs region -- allocated, never used).
        {
            int idx = min(3 * r + w, nt - 1);
            const char* rowp = (const char*)(cw + (size_t)toks[idx] * CWS);
            char* lbase = (char*)&rows[w][0];
            #pragma unroll
            for (int jj = 0; jj < 3; ++jj)
                gload_lds16(rowp + jj * 1024 + lane * 16,
                            lbase + jj * 1024 + lane * 16);
        }
        __syncthreads();                 // DMA complete, rows readable

        #pragma unroll
        for (int u = 0; u < 3; ++u) {
            int i2 = 3 * r + u;
            if (i2 >= nt) break;
            if (p < P_) {
                const float* rp = &rows[u][p * 5];
                float c0 = rp[0], c1 = rp[1], c2 = rp[2], c3 = rp[3], c4 = rp[4];
                h5 = h4 + c4;
                h4 = h3 + c3;
                h3 = h2 + c2;
                h2 = h1 + c1;
                h1 = c0;                 // h0 = 0 always
                if (i2 >= warm_n) {
                    float esv = (e == 3) ? h3 : (e == 4) ? h4 : h5;
                    sc = fmaxf(sc, esv);
                }
            }
        }
        __syncthreads();                 // protect rows before next DMA round
    }
    if (p < P_) cs[(size_t)(b * NCHUNK + ci) * CS_STRIDE + p] = sc;
}

__device__ __forceinline__ float block_sum192(float v, volatile float* red, int tid) {
    #pragma unroll
    for (int off = 32; off > 0; off >>= 1) v += __shfl_down(v, off, 64);
    __syncthreads();
    if ((tid & 63) == 0) red[tid >> 6] = v;
    __syncthreads();
    return red[0] + red[1] + red[2];
}

__global__ __launch_bounds__(192) void k3_final(
    const float* __restrict__ cs,
    const float* __restrict__ gamma,
    const float* __restrict__ beta,
    const float* __restrict__ lw,
    const float* __restrict__ lb,
    float* __restrict__ out)
{
    __shared__ float red[3];
    const int b   = blockIdx.x;
    const int tid = threadIdx.x;
    float s = 0.f;
    if (tid < P_) {
        float m = NEGF;
        const float* row = cs + (size_t)b * NCHUNK * CS_STRIDE + tid;
        #pragma unroll
        for (int ci = 0; ci < NCHUNK; ++ci) m = fmaxf(m, row[ci * CS_STRIDE]);
        s = expf(m);
    }
    float mu = block_sum192(s, red, tid) * (1.f / P_);
    float d  = (tid < P_) ? (s - mu) : 0.f;
    float var = block_sum192(d * d, red, tid) * (1.f / P_);
    float bin = 0.f;
    if (tid < P_) {
        float norm = (s - mu) * rsqrtf(var + 1e-5f) * gamma[tid] + beta[tid];
        bin = (norm > 0.f) ? 1.f : 0.f;
    }
    float o0 = block_sum192((tid < P_) ? bin * lw[tid]      : 0.f, red, tid);
    float o1 = block_sum192((tid < P_) ? bin * lw[P_ + tid] : 0.f, red, tid);
    if (tid == 0) {
        out[b * 2 + 0] = o0 + lb[0];
        out[b * 2 + 1] = o1 + lb[1];
    }
}

extern "C" void kernel_launch(void* const* d_in, const int* in_sizes, int n_in,
                              void* d_out, int out_size, void* d_ws, size_t ws_size,
                              hipStream_t stream)
{
    const int*   docs  = (const int*)  d_in[0];
    const int*   dlens = (const int*)  d_in[1];
    const float* emb   = (const float*)d_in[2];
    const float* diags = (const float*)d_in[3];
    const float* bias  = (const float*)d_in[4];
    const float* wildc = (const float*)d_in[5];
    const float* gamma = (const float*)d_in[6];
    const float* beta  = (const float*)d_in[7];
    const float* lw    = (const float*)d_in[8];
    const float* lb    = (const float*)d_in[9];
    float* out = (float*)d_out;

    // ws layout: cw | cs | a_t | b_t
    const size_t cw_b = (size_t)V_ * CWS * 4;                 // 60,160,000
    const size_t cs_b = (size_t)B_ * NCHUNK * CS_STRIDE * 4;  // 655,360
    const size_t at_b = (size_t)NVG * NIT * TILE_U4 * 16;     // 25,722,880
    const size_t bt_b = (size_t)NJ  * NIT * TILE_U4 * 16;     // 983,040
    const size_t need = cw_b + cs_b + at_b + bt_b;

    char* base = (char*)d_ws;
    float* cw = (float*)base;
    float* cs = (float*)(base + cw_b);
    uint4* at = (uint4*)(base + cw_b + cs_b);
    uint4* bt = (uint4*)(base + cw_b + cs_b + at_b);

    if (ws_size >= need) {
        p1_split_a<<<dim3(NVG, 5), 256, 0, stream>>>(emb, at);
        p2_split_b<<<NJ * NIT, 256, 0, stream>>>(diags, bt);
        // 1-D grid, XCD-colocated siblings: 160 v-group slots x 6 n-groups = 960
        k1m_gemm<<<960, 256, 0, stream>>>(at, bt, bias, wildc, cw);
    } else {
        dim3 g1((V_ + BM - 1) / BM, (NOUT + BN - 1) / BN);
        k1_gemm_cw<<<g1, 256, 0, stream>>>(emb, diags, bias, wildc, cw);
    }

    dim3 g2(NCHUNK, B_);
    k2_scan<<<g2, 192, 0, stream>>>(docs, dlens, cw, cs);
    k3_final<<<B_, 192, 0, stream>>>(cs, gamma, beta, lw, lb, out);
}

// Round 9
// 150.826 us; speedup vs baseline: 1.0174x; 1.0174x over previous
//
#include <hip/hip_runtime.h>
#include <hip/hip_bf16.h>
#include <hip/hip_fp16.h>
#include <math.h>

// Problem constants (from reference)
#define B_   64
#define L_   512
#define V_   20000
#define P_   150
#define M_   6
#define KDIM 300
#define NOUT 750          // P_ * (M_-1) used transition scores
#define CWS  752          // padded row stride (16B-aligned float4 rows)
#define NEGF (-1.0e9f)

// f32 fallback GEMM tiling
#define BM 128
#define BN 128
#define BK 16
#define LDP 132

// MFMA path constants
#define KP 320            // K padded: 10 tiles of 32
#define NIT 10            // K-iters
#define NVG 157           // v-groups of 128
#define NJ  6             // n-groups of 128 (b_t layout unit)
#define TILE_U4 1024      // uint4 per (group,it) tile: [s 2][q 4][row 128]
#define SA 1024.0f        // emb scale (keeps lo-split out of fp16 subnormals)
#define SB 16384.0f       // diags scale
#define INV24 (5.9604644775390625e-8f)   // 2^-24

// Scan chunking
#define TCHUNK 32
#define NCHUNK (L_ / TCHUNK)   // 16
#define WARM   5
#define CS_STRIDE 160

typedef _Float16 f16x8 __attribute__((ext_vector_type(8)));
typedef float f32x16 __attribute__((ext_vector_type(16)));

__device__ __forceinline__ float logsigf(float x) {
    // matches jax: -softplus(-x) = min(x,0) - log1p(exp(-|x|))
    return fminf(x, 0.f) - log1pf(expf(-fabsf(x)));
}

// fast variant for k1m epilogue: v_exp_f32/v_log_f32, abs err ~6e-8 (flip-safe budget)
__device__ __forceinline__ float logsigf_fast(float x) {
    return fminf(x, 0.f) - __logf(1.f + __expf(-fabsf(x)));
}

// async global->LDS, 16 B per lane; LDS dst = wave-uniform base + lane*16
__device__ __forceinline__ void gload_lds16(const void* gp, void* lp) {
    __builtin_amdgcn_global_load_lds(
        (const __attribute__((address_space(1))) unsigned int*)gp,
        (__attribute__((address_space(3))) unsigned int*)lp, 16, 0, 0);
}

// ---------------- MFMA path ----------------

// P12 (fused p1+p2, one launch):
// blocks [0, NVG*5): emb [300][20000] -> fp16 hi/lo splits, DMA-tiled
//   a_t[g 157][it 10][s 2][q 4][row 128] uint4.
// blocks [NVG*5, NVG*5+60): diags (dpm-mapped, scaled) -> b_t[j 6][it 10][s2][q4][row128].
__global__ __launch_bounds__(256) void p12_split(
    const float* __restrict__ emb, const float* __restrict__ diags,
    uint4* __restrict__ a_t, uint4* __restrict__ b_t)
{
    __shared__ float T[64][132];
    const int t   = threadIdx.x;
    const int bid = blockIdx.x;

    if (bid < NVG * 5) {
        // ---- p1 part ----
        const int gx = bid % NVG;
        const int ky = bid / NVG;            // 0..4
        const int v0 = gx * 128;
        const int k0 = ky * 64;

        #pragma unroll
        for (int pass = 0; pass < 8; ++pass) {
            int flat = pass * 256 + t;
            int krow = flat >> 5;
            int c4   = (flat & 31) * 4;
            int kg   = k0 + krow;
            int v    = v0 + c4;
            float4 f = {0.f, 0.f, 0.f, 0.f};
            if (kg < KDIM && v + 3 < V_)
                f = *(const float4*)(emb + (size_t)kg * V_ + v);
            *(float4*)&T[krow][c4] = f;
        }
        __syncthreads();

        const int vv = t >> 1;
        const int kh = (t & 1) * 32;
        const int it = ky * 2 + (kh >> 5);
        const int v  = v0 + vv;
        if (v < V_) {
            union { ushort u[8]; uint4 q; } H[4], Lo[4];
            #pragma unroll
            for (int i = 0; i < 32; ++i) {
                float x = T[kh + i][vv] * SA;
                __half h = __float2half_rn(x);
                float rem = x - __half2float(h);
                H[i >> 3].u[i & 7]  = __half_as_ushort(h);
                Lo[i >> 3].u[i & 7] = __half_as_ushort(__float2half_rn(rem));
            }
            uint4* tile = a_t + ((size_t)gx * NIT + it) * TILE_U4;
            #pragma unroll
            for (int c = 0; c < 4; ++c) {
                tile[      c * 128 + vv] = H[c].q;
                tile[512 + c * 128 + vv] = Lo[c].q;
            }
        }
    } else {
        // ---- p2 part ----
        const int bidx = bid - NVG * 5;      // j*10 + it, 0..59
        const int it   = bidx % NIT;
        const int j    = bidx / NIT;
        const int row  = t >> 1;
        const int qh   = (t & 1) * 2;
        const int n    = j * 128 + row;
        const bool nok = (n < NOUT);
        const int pm   = nok ? ((n / 5) * 6 + (n % 5)) : 0;
        uint4* tile = b_t + (size_t)bidx * TILE_U4;
        #pragma unroll
        for (int qq = 0; qq < 2; ++qq) {
            int q = qh + qq;
            union { ushort u[8]; uint4 v; } H, Lo;
            #pragma unroll
            for (int e = 0; e < 8; ++e) {
                int k = it * 32 + q * 8 + e;
                float x = (nok && k < KDIM) ? diags[(size_t)pm * KDIM + k] * SB : 0.f;
                __half h = __float2half_rn(x);
                float rem = x - __half2float(h);
                H.u[e]  = __half_as_ushort(h);
                Lo.u[e] = __half_as_ushort(__float2half_rn(rem));
            }
            tile[      q * 128 + row] = H.v;
            tile[512 + q * 128 + row] = Lo.v;
        }
    }
}

// K1 (MFMA): C = a1@b1 + a1@b2 + a2@b1 (fp16 split-f32), 128v x 256n tile.
// 48 KB LDS: A-hi[512] A-lo[512] B-hi[2x512] B-lo[2x512] uint4.
// Per barrier each wave issues 48 MFMAs (2x r8) -> half the device-wide barrier
// drains, A-fetch amortized over 2x outputs. Waves 0/1 stage A hi/lo (8 KB),
// waves 2/3 stage B hi/lo (16 KB) via contiguous 1 KB global_load_lds.
// Grid 480: bid%8 = XCD, 3 siblings sharing a_t[g] colocated per XCD.
__global__ __launch_bounds__(256, 2) void k1m_gemm(
    const uint4* __restrict__ a_t, const uint4* __restrict__ b_t,
    const float* __restrict__ bias, const float* __restrict__ wildc,
    float* __restrict__ cw)
{
    const int bid  = blockIdx.x;
    const int xcd  = bid & 7;
    const int slot = bid >> 3;               // 0..59
    const int g    = xcd + 8 * (slot / 3);   // v-group 0..159
    const int jp   = slot % 3;               // n-group of 256
    if (g >= NVG) return;

    __shared__ uint4 sm[3072];               // 48 KB
    const int t    = threadIdx.x;
    const int lane = t & 63;
    const int w    = t >> 6;
    const int wr   = w >> 1, wc = w & 1;
    const int v0   = g * 128;
    const int n0   = jp * 256;

    const int fk16 = lane >> 5;
    const int fm   = lane & 31;

    f32x16 acc[2][4];
    #pragma unroll
    for (int i = 0; i < 2; ++i)
        #pragma unroll
        for (int jj = 0; jj < 4; ++jj)
            #pragma unroll
            for (int r = 0; r < 16; ++r) acc[i][jj][r] = 0.f;

    for (int it = 0; it < NIT; ++it) {
        // stage: A-waves 8 KB, B-waves 16 KB, all contiguous 1 KB DMA instrs
        if (w < 2) {
            const uint4* gp = a_t + ((size_t)g * NIT + it) * TILE_U4 + w * 512 + lane;
            #pragma unroll
            for (int i = 0; i < 8; ++i)
                gload_lds16(gp + i * 64, &sm[w * 512 + i * 64 + lane]);
        } else {
            const int s = w - 2;             // 0 = hi, 1 = lo
            #pragma unroll
            for (int jt = 0; jt < 2; ++jt) {
                const uint4* gp = b_t + ((size_t)(2 * jp + jt) * NIT + it) * TILE_U4
                                      + s * 512 + lane;
                #pragma unroll
                for (int i = 0; i < 8; ++i)
                    gload_lds16(gp + i * 64,
                                &sm[1024 + s * 1024 + jt * 512 + i * 64 + lane]);
            }
        }
        __syncthreads();                     // drains vmcnt: LDS tiles complete

        #pragma unroll
        for (int s = 0; s < 2; ++s) {
            f16x8 A1[2], A2[2], B1[4], B2[4];
            const int q = s * 2 + fk16;
            #pragma unroll
            for (int ri = 0; ri < 2; ++ri) {
                A1[ri] = *(const f16x8*)&sm[        q * 128 + wr * 64 + ri * 32 + fm];
                A2[ri] = *(const f16x8*)&sm[512   + q * 128 + wr * 64 + ri * 32 + fm];
            }
            #pragma unroll
            for (int cj = 0; cj < 4; ++cj) {
                B1[cj] = *(const f16x8*)&sm[1024 + wc * 512 + q * 128 + cj * 32 + fm];
                B2[cj] = *(const f16x8*)&sm[2048 + wc * 512 + q * 128 + cj * 32 + fm];
            }
            #pragma unroll
            for (int ri = 0; ri < 2; ++ri)
                #pragma unroll
                for (int cj = 0; cj < 4; ++cj) {
                    acc[ri][cj] = __builtin_amdgcn_mfma_f32_32x32x16_f16(A1[ri], B1[cj], acc[ri][cj], 0, 0, 0);
                    acc[ri][cj] = __builtin_amdgcn_mfma_f32_32x32x16_f16(A1[ri], B2[cj], acc[ri][cj], 0, 0, 0);
                    acc[ri][cj] = __builtin_amdgcn_mfma_f32_32x32x16_f16(A2[ri], B1[cj], acc[ri][cj], 0, 0, 0);
                }
        }
        __syncthreads();                     // protect LDS before next stage
    }

    // epilogue: C/D layout col=lane&31, row=(r&3)+8*(r>>2)+4*(lane>>5)
    float biasv[4], lwv[4]; int ncol[4]; bool nok[4];
    #pragma unroll
    for (int cj = 0; cj < 4; ++cj) {
        int n = n0 + wc * 128 + cj * 32 + fm;
        ncol[cj] = n;
        nok[cj]  = (n < NOUT);
        int nc = nok[cj] ? n : 0;
        int pm = (nc / 5) * 6 + (nc % 5);
        biasv[cj] = bias[pm];
        lwv[cj]   = logsigf_fast(wildc[nc]);
    }
    #pragma unroll
    for (int ri = 0; ri < 2; ++ri) {
        int vbase = v0 + wr * 64 + ri * 32 + 4 * fk16;
        #pragma unroll
        for (int cj = 0; cj < 4; ++cj) {
            if (!nok[cj]) continue;
            #pragma unroll
            for (int r = 0; r < 16; ++r) {
                int v = vbase + (r & 3) + 8 * (r >> 2);
                if (v < V_) {
                    float val = acc[ri][cj][r] * INV24 + biasv[cj];
                    cw[(size_t)v * CWS + ncol[cj]] = fmaxf(logsigf_fast(val), lwv[cj]);
                }
            }
        }
    }
}

// ---------------- f32 fallback (round-2 kernel) ----------------

__global__ __launch_bounds__(256) void k1_gemm_cw(
    const float* __restrict__ emb,
    const float* __restrict__ diags,
    const float* __restrict__ bias,
    const float* __restrict__ wildc,
    float* __restrict__ cw)
{
    __shared__ float As[BK][LDP];
    __shared__ float Bs[BK][LDP];

    const int tid = threadIdx.x;
    const int v0 = blockIdx.x * BM;
    const int n0 = blockIdx.y * BN;
    const int tx = tid & 15;
    const int ty = tid >> 4;

    float acc[8][8];
    #pragma unroll
    for (int i = 0; i < 8; ++i)
        #pragma unroll
        for (int j = 0; j < 8; ++j) acc[i][j] = 0.f;

    const int a_k = tid >> 4;
    const int a_v = (tid & 15) * 8;
    const int b_n   = tid >> 1;
    const int b_kof = (tid & 1) * 8;

    int  brow;
    bool bval;
    {
        int n = n0 + b_n;
        bval = (n < NOUT);
        brow = bval ? ((n / 5) * 6 + (n % 5)) : 0;
    }

    for (int k0 = 0; k0 < KDIM; k0 += BK) {
        {
            float4 f0 = {0,0,0,0}, f1 = {0,0,0,0};
            int k = k0 + a_k;
            if (k < KDIM) {
                const float* src = emb + (size_t)k * V_ + v0 + a_v;
                if (v0 + a_v + 3 < V_) f0 = *(const float4*)src;
                if (v0 + a_v + 7 < V_) f1 = *(const float4*)(src + 4);
            }
            *(float4*)&As[a_k][a_v]     = f0;
            *(float4*)&As[a_k][a_v + 4] = f1;
        }
        {
            float4 f = {0,0,0,0}, g = {0,0,0,0};
            if (bval) {
                const float* src = diags + (size_t)brow * KDIM + k0 + b_kof;
                if (k0 + b_kof + 3 < KDIM) f = *(const float4*)src;
                if (k0 + b_kof + 7 < KDIM) g = *(const float4*)(src + 4);
            }
            Bs[b_kof + 0][b_n] = f.x;
            Bs[b_kof + 1][b_n] = f.y;
            Bs[b_kof + 2][b_n] = f.z;
            Bs[b_kof + 3][b_n] = f.w;
            Bs[b_kof + 4][b_n] = g.x;
            Bs[b_kof + 5][b_n] = g.y;
            Bs[b_kof + 6][b_n] = g.z;
            Bs[b_kof + 7][b_n] = g.w;
        }
        __syncthreads();
        #pragma unroll
        for (int k = 0; k < BK; ++k) {
            float4 a0 = *(const float4*)&As[k][tx * 4];
            float4 a1 = *(const float4*)&As[k][64 + tx * 4];
            float4 b0 = *(const float4*)&Bs[k][ty * 8];
            float4 b1 = *(const float4*)&Bs[k][ty * 8 + 4];
            float av[8] = {a0.x, a0.y, a0.z, a0.w, a1.x, a1.y, a1.z, a1.w};
            float bv[8] = {b0.x, b0.y, b0.z, b0.w, b1.x, b1.y, b1.z, b1.w};
            #pragma unroll
            for (int i = 0; i < 8; ++i)
                #pragma unroll
                for (int j = 0; j < 8; ++j)
                    acc[i][j] = fmaf(av[i], bv[j], acc[i][j]);
        }
        __syncthreads();
    }

    float biasv[8], lwv[8];
    #pragma unroll
    for (int j = 0; j < 8; ++j) {
        int n  = n0 + ty * 8 + j;
        int nc = (n < NOUT) ? n : 0;
        int pm = (nc / 5) * 6 + (nc % 5);
        biasv[j] = bias[pm];
        lwv[j]   = logsigf(wildc[nc]);
    }
    #pragma unroll
    for (int i = 0; i < 8; ++i) {
        int v = v0 + ((i < 4) ? (tx * 4 + i) : (64 + tx * 4 + (i - 4)));
        if (v >= V_) continue;
        float r[8];
        #pragma unroll
        for (int j = 0; j < 8; ++j)
            r[j] = fmaxf(logsigf(acc[i][j] + biasv[j]), lwv[j]);
        float* dst = cw + (size_t)v * CWS + n0 + ty * 8;
        if (n0 + ty * 8     < NOUT) *(float4*)dst       = make_float4(r[0], r[1], r[2], r[3]);
        if (n0 + ty * 8 + 4 < NOUT) *(float4*)(dst + 4) = make_float4(r[4], r[5], r[6], r[7]);
    }
}

// ---------------- scan (cooperative LDS staging) + finalize ----------------

__global__ __launch_bounds__(192) void k2_scan(
    const int* __restrict__ docs,
    const int* __restrict__ doc_lens,
    const float* __restrict__ cw,
    float* __restrict__ cs)
{
    const int ci = blockIdx.x;
    const int b  = blockIdx.y;
    const int t0 = ci * TCHUNK;
    const int ts = (t0 >= WARM) ? (t0 - WARM) : 0;
    const int dl = doc_lens[b];
    const int te = min(t0 + TCHUNK, dl);
    const int nt = te - ts;              // tokens to process (may be <= 0)

    __shared__ int   toks[TCHUNK + WARM];
    __shared__ float rows[3][768];       // 3 KB rows (750 used + pad)

    const int t    = threadIdx.x;
    const int lane = t & 63;
    const int w    = t >> 6;             // wave 0..2

    if (t < TCHUNK + WARM) {
        int tt = ts + t;
        toks[t] = docs[b * L_ + min(tt, L_ - 1)];
    }
    __syncthreads();

    const int p      = t;                // pattern if < P_
    const int e      = (p < 50) ? 3 : (p < 100) ? 4 : 5;
    const int warm_n = t0 - ts;
    float h1 = NEGF, h2 = NEGF, h3 = NEGF, h4 = NEGF, h5 = NEGF, sc = NEGF;

    const int nrounds = (nt > 0) ? (nt + 2) / 3 : 0;
    for (int r = 0; r < nrounds; ++r) {
        {
            int idx = min(3 * r + w, nt - 1);
            const char* rowp = (const char*)(cw + (size_t)toks[idx] * CWS);
            char* lbase = (char*)&rows[w][0];
            #pragma unroll
            for (int jj = 0; jj < 3; ++jj)
                gload_lds16(rowp + jj * 1024 + lane * 16,
                            lbase + jj * 1024 + lane * 16);
        }
        __syncthreads();                 // DMA complete, rows readable

        #pragma unroll
        for (int u = 0; u < 3; ++u) {
            int i2 = 3 * r + u;
            if (i2 >= nt) break;
            if (p < P_) {
                const float* rp = &rows[u][p * 5];
                float c0 = rp[0], c1 = rp[1], c2 = rp[2], c3 = rp[3], c4 = rp[4];
                h5 = h4 + c4;
                h4 = h3 + c3;
                h3 = h2 + c2;
                h2 = h1 + c1;
                h1 = c0;                 // h0 = 0 always
                if (i2 >= warm_n) {
                    float esv = (e == 3) ? h3 : (e == 4) ? h4 : h5;
                    sc = fmaxf(sc, esv);
                }
            }
        }
        __syncthreads();                 // protect rows before next DMA round
    }
    if (p < P_) cs[(size_t)(b * NCHUNK + ci) * CS_STRIDE + p] = sc;
}

__device__ __forceinline__ float block_sum192(float v, volatile float* red, int tid) {
    #pragma unroll
    for (int off = 32; off > 0; off >>= 1) v += __shfl_down(v, off, 64);
    __syncthreads();
    if ((tid & 63) == 0) red[tid >> 6] = v;
    __syncthreads();
    return red[0] + red[1] + red[2];
}

__global__ __launch_bounds__(192) void k3_final(
    const float* __restrict__ cs,
    const float* __restrict__ gamma,
    const float* __restrict__ beta,
    const float* __restrict__ lw,
    const float* __restrict__ lb,
    float* __restrict__ out)
{
    __shared__ float red[3];
    const int b   = blockIdx.x;
    const int tid = threadIdx.x;
    float s = 0.f;
    if (tid < P_) {
        float m = NEGF;
        const float* row = cs + (size_t)b * NCHUNK * CS_STRIDE + tid;
        #pragma unroll
        for (int ci = 0; ci < NCHUNK; ++ci) m = fmaxf(m, row[ci * CS_STRIDE]);
        s = expf(m);
    }
    float mu = block_sum192(s, red, tid) * (1.f / P_);
    float d  = (tid < P_) ? (s - mu) : 0.f;
    float var = block_sum192(d * d, red, tid) * (1.f / P_);
    float bin = 0.f;
    if (tid < P_) {
        float norm = (s - mu) * rsqrtf(var + 1e-5f) * gamma[tid] + beta[tid];
        bin = (norm > 0.f) ? 1.f : 0.f;
    }
    float o0 = block_sum192((tid < P_) ? bin * lw[tid]      : 0.f, red, tid);
    float o1 = block_sum192((tid < P_) ? bin * lw[P_ + tid] : 0.f, red, tid);
    if (tid == 0) {
        out[b * 2 + 0] = o0 + lb[0];
        out[b * 2 + 1] = o1 + lb[1];
    }
}

extern "C" void kernel_launch(void* const* d_in, const int* in_sizes, int n_in,
                              void* d_out, int out_size, void* d_ws, size_t ws_size,
                              hipStream_t stream)
{
    const int*   docs  = (const int*)  d_in[0];
    const int*   dlens = (const int*)  d_in[1];
    const float* emb   = (const float*)d_in[2];
    const float* diags = (const float*)d_in[3];
    const float* bias  = (const float*)d_in[4];
    const float* wildc = (const float*)d_in[5];
    const float* gamma = (const float*)d_in[6];
    const float* beta  = (const float*)d_in[7];
    const float* lw    = (const float*)d_in[8];
    const float* lb    = (const float*)d_in[9];
    float* out = (float*)d_out;

    // ws layout: cw | cs | a_t | b_t
    const size_t cw_b = (size_t)V_ * CWS * 4;                 // 60,160,000
    const size_t cs_b = (size_t)B_ * NCHUNK * CS_STRIDE * 4;  // 655,360
    const size_t at_b = (size_t)NVG * NIT * TILE_U4 * 16;     // 25,722,880
    const size_t bt_b = (size_t)NJ  * NIT * TILE_U4 * 16;     // 983,040
    const size_t need = cw_b + cs_b + at_b + bt_b;

    char* base = (char*)d_ws;
    float* cw = (float*)base;
    float* cs = (float*)(base + cw_b);
    uint4* at = (uint4*)(base + cw_b + cs_b);
    uint4* bt = (uint4*)(base + cw_b + cs_b + at_b);

    if (ws_size >= need) {
        p12_split<<<NVG * 5 + NJ * NIT, 256, 0, stream>>>(emb, diags, at, bt);
        // 1-D grid, XCD-colocated siblings: 160 v-group slots x 3 n-groups = 480
        k1m_gemm<<<480, 256, 0, stream>>>(at, bt, bias, wildc, cw);
    } else {
        dim3 g1((V_ + BM - 1) / BM, (NOUT + BN - 1) / BN);
        k1_gemm_cw<<<g1, 256, 0, stream>>>(emb, diags, bias, wildc, cw);
    }

    dim3 g2(NCHUNK, B_);
    k2_scan<<<g2, 192, 0, stream>>>(docs, dlens, cw, cs);
    k3_final<<<B_, 192, 0, stream>>>(cs, gamma, beta, lw, lb, out);
}

// Round 10
// 148.374 us; speedup vs baseline: 1.0342x; 1.0165x over previous
//
#include <hip/hip_runtime.h>
#include <hip/hip_bf16.h>
#include <hip/hip_fp16.h>
#include <math.h>

// Problem constants (from reference)
#define B_   64
#define L_   512
#define V_   20000
#define P_   150
#define M_   6
#define KDIM 300
#define NOUT 750          // P_ * (M_-1) used transition scores
#define CWS  752          // padded row stride (16B-aligned float4 rows)
#define NEGF (-1.0e9f)

// f32 fallback GEMM tiling
#define BM 128
#define BN 128
#define BK 16
#define LDP 132

// MFMA path constants
#define KP 320            // K padded: 10 tiles of 32
#define NIT 10            // K-iters
#define NVG 157           // v-groups of 128
#define NJ  6             // n-groups of 128
#define TILE_U4 1024      // uint4 per (group,it) tile: [s 2][q 4][row 128]
#define SA 1024.0f        // emb scale (keeps lo-split out of fp16 subnormals)
#define SB 16384.0f       // diags scale
#define INV24 (5.9604644775390625e-8f)   // 2^-24

// Scan chunking
#define TCHUNK 32
#define NCHUNK (L_ / TCHUNK)   // 16
#define WARM   5
#define CS_STRIDE 160

typedef _Float16 f16x8 __attribute__((ext_vector_type(8)));
typedef float f32x16 __attribute__((ext_vector_type(16)));

__device__ __forceinline__ float logsigf(float x) {
    // matches jax: -softplus(-x) = min(x,0) - log1p(exp(-|x|))
    return fminf(x, 0.f) - log1pf(expf(-fabsf(x)));
}

// fast variant for k1m epilogue: v_exp_f32/v_log_f32, abs err ~6e-8 (flip-safe budget)
__device__ __forceinline__ float logsigf_fast(float x) {
    return fminf(x, 0.f) - __logf(1.f + __expf(-fabsf(x)));
}

// async global->LDS, 16 B per lane; LDS dst = wave-uniform base + lane*16
__device__ __forceinline__ void gload_lds16(const void* gp, void* lp) {
    __builtin_amdgcn_global_load_lds(
        (const __attribute__((address_space(1))) unsigned int*)gp,
        (__attribute__((address_space(3))) unsigned int*)lp, 16, 0, 0);
}

// ---------------- MFMA path ----------------

// P12 (fused p1+p2, one launch):
// blocks [0, NVG*5): emb [300][20000] -> fp16 hi/lo splits, DMA-tiled
//   a_t[g 157][it 10][s 2][q 4][row 128] uint4.
// blocks [NVG*5, NVG*5+60): diags (dpm-mapped, scaled) -> b_t[j 6][it 10][s2][q4][row128].
__global__ __launch_bounds__(256) void p12_split(
    const float* __restrict__ emb, const float* __restrict__ diags,
    uint4* __restrict__ a_t, uint4* __restrict__ b_t)
{
    __shared__ float T[64][132];
    const int t   = threadIdx.x;
    const int bid = blockIdx.x;

    if (bid < NVG * 5) {
        // ---- p1 part ----
        const int gx = bid % NVG;
        const int ky = bid / NVG;            // 0..4
        const int v0 = gx * 128;
        const int k0 = ky * 64;

        #pragma unroll
        for (int pass = 0; pass < 8; ++pass) {
            int flat = pass * 256 + t;
            int krow = flat >> 5;
            int c4   = (flat & 31) * 4;
            int kg   = k0 + krow;
            int v    = v0 + c4;
            float4 f = {0.f, 0.f, 0.f, 0.f};
            if (kg < KDIM && v + 3 < V_)
                f = *(const float4*)(emb + (size_t)kg * V_ + v);
            *(float4*)&T[krow][c4] = f;
        }
        __syncthreads();

        const int vv = t >> 1;
        const int kh = (t & 1) * 32;
        const int it = ky * 2 + (kh >> 5);
        const int v  = v0 + vv;
        if (v < V_) {
            union { ushort u[8]; uint4 q; } H[4], Lo[4];
            #pragma unroll
            for (int i = 0; i < 32; ++i) {
                float x = T[kh + i][vv] * SA;
                __half h = __float2half_rn(x);
                float rem = x - __half2float(h);
                H[i >> 3].u[i & 7]  = __half_as_ushort(h);
                Lo[i >> 3].u[i & 7] = __half_as_ushort(__float2half_rn(rem));
            }
            uint4* tile = a_t + ((size_t)gx * NIT + it) * TILE_U4;
            #pragma unroll
            for (int c = 0; c < 4; ++c) {
                tile[      c * 128 + vv] = H[c].q;
                tile[512 + c * 128 + vv] = Lo[c].q;
            }
        }
    } else {
        // ---- p2 part ----
        const int bidx = bid - NVG * 5;      // j*10 + it, 0..59
        const int it   = bidx % NIT;
        const int j    = bidx / NIT;
        const int row  = t >> 1;
        const int qh   = (t & 1) * 2;
        const int n    = j * 128 + row;
        const bool nok = (n < NOUT);
        const int pm   = nok ? ((n / 5) * 6 + (n % 5)) : 0;
        uint4* tile = b_t + (size_t)bidx * TILE_U4;
        #pragma unroll
        for (int qq = 0; qq < 2; ++qq) {
            int q = qh + qq;
            union { ushort u[8]; uint4 v; } H, Lo;
            #pragma unroll
            for (int e = 0; e < 8; ++e) {
                int k = it * 32 + q * 8 + e;
                float x = (nok && k < KDIM) ? diags[(size_t)pm * KDIM + k] * SB : 0.f;
                __half h = __float2half_rn(x);
                float rem = x - __half2float(h);
                H.u[e]  = __half_as_ushort(h);
                Lo.u[e] = __half_as_ushort(__float2half_rn(rem));
            }
            tile[      q * 128 + row] = H.v;
            tile[512 + q * 128 + row] = Lo.v;
        }
    }
}

// K1 (MFMA): C = a1@b1 + a1@b2 + a2@b1 (fp16 split-f32), 128x128 tile (r8 config)
// + DOUBLE-BUFFERED async staging: DMA for iter it+1 is issued into the other
// 32 KB buffer right after the barrier, then 48 MFMAs overlap it. The barrier
// at the top of iter it+1 drains that DMA (vmcnt(0)), which by then had a full
// compute phase to complete -> exposed wait ~max(0, DMA - compute) instead of
// DMA + compute. One barrier per iter. 64 KB LDS, 2 blocks/CU.
// Wave w stages section w (A-hi, A-lo, B-hi, B-lo), contiguous 1 KB per DMA.
// Grid 960: bid%8 = XCD, 6 siblings sharing a_t[g] colocated per XCD.
__global__ __launch_bounds__(256, 2) void k1m_gemm(
    const uint4* __restrict__ a_t, const uint4* __restrict__ b_t,
    const float* __restrict__ bias, const float* __restrict__ wildc,
    float* __restrict__ cw)
{
    const int bid  = blockIdx.x;
    const int xcd  = bid & 7;
    const int slot = bid >> 3;               // 0..119
    const int g    = xcd + 8 * (slot / 6);   // v-group 0..159
    const int j    = slot % 6;               // n-group
    if (g >= NVG) return;

    __shared__ uint4 sm[2][2048];            // 2 x 32 KB = 64 KB
    const int t    = threadIdx.x;
    const int lane = t & 63;
    const int w    = t >> 6;
    const int wr   = w >> 1, wc = w & 1;
    const int v0   = g * 128;
    const int n0   = j * 128;

    // wave w's tiled global section base (contiguous per iter)
    const uint4* gsec = (w < 2)
        ? a_t + (size_t)g * NIT * TILE_U4 + w * 512
        : b_t + (size_t)j * NIT * TILE_U4 + (w - 2) * 512;

    const int fk16 = lane >> 5;
    const int fm   = lane & 31;

    f32x16 acc[2][2];
    #pragma unroll
    for (int i = 0; i < 2; ++i)
        #pragma unroll
        for (int jj = 0; jj < 2; ++jj)
            #pragma unroll
            for (int r = 0; r < 16; ++r) acc[i][jj][r] = 0.f;

    // prologue: stage it=0 into buffer 0
    {
        const uint4* gp = gsec + lane;
        #pragma unroll
        for (int i = 0; i < 8; ++i)
            gload_lds16(gp + i * 64, &sm[0][w * 512 + i * 64 + lane]);
    }

    int cur = 0;
    for (int it = 0; it < NIT; ++it) {
        __syncthreads();                     // drains DMA for buf[cur]; fences prev compute

        if (it + 1 < NIT) {                  // async prefetch into the other buffer
            const uint4* gp = gsec + (size_t)(it + 1) * TILE_U4 + lane;
            #pragma unroll
            for (int i = 0; i < 8; ++i)
                gload_lds16(gp + i * 64, &sm[cur ^ 1][w * 512 + i * 64 + lane]);
        }

        const uint4* smc = sm[cur];
        #pragma unroll
        for (int s = 0; s < 2; ++s) {
            f16x8 A1[2], A2[2], B1[2], B2[2];
            const int q = s * 2 + fk16;
            #pragma unroll
            for (int ri = 0; ri < 2; ++ri) {
                A1[ri] = *(const f16x8*)&smc[(0 * 4 + q) * 128 + wr * 64 + ri * 32 + fm];
                A2[ri] = *(const f16x8*)&smc[(1 * 4 + q) * 128 + wr * 64 + ri * 32 + fm];
            }
            #pragma unroll
            for (int cj = 0; cj < 2; ++cj) {
                B1[cj] = *(const f16x8*)&smc[(2 * 4 + q) * 128 + wc * 64 + cj * 32 + fm];
                B2[cj] = *(const f16x8*)&smc[(3 * 4 + q) * 128 + wc * 64 + cj * 32 + fm];
            }
            #pragma unroll
            for (int ri = 0; ri < 2; ++ri)
                #pragma unroll
                for (int cj = 0; cj < 2; ++cj) {
                    acc[ri][cj] = __builtin_amdgcn_mfma_f32_32x32x16_f16(A1[ri], B1[cj], acc[ri][cj], 0, 0, 0);
                    acc[ri][cj] = __builtin_amdgcn_mfma_f32_32x32x16_f16(A1[ri], B2[cj], acc[ri][cj], 0, 0, 0);
                    acc[ri][cj] = __builtin_amdgcn_mfma_f32_32x32x16_f16(A2[ri], B1[cj], acc[ri][cj], 0, 0, 0);
                }
        }
        cur ^= 1;
    }

    // epilogue: C/D layout col=lane&31, row=(r&3)+8*(r>>2)+4*(lane>>5)
    float biasv[2], lwv[2]; int ncol[2]; bool nok[2];
    #pragma unroll
    for (int cj = 0; cj < 2; ++cj) {
        int n = n0 + wc * 64 + cj * 32 + fm;
        ncol[cj] = n;
        nok[cj]  = (n < NOUT);
        int nc = nok[cj] ? n : 0;
        int pm = (nc / 5) * 6 + (nc % 5);
        biasv[cj] = bias[pm];
        lwv[cj]   = logsigf_fast(wildc[nc]);
    }
    #pragma unroll
    for (int ri = 0; ri < 2; ++ri) {
        int vbase = v0 + wr * 64 + ri * 32 + 4 * fk16;
        #pragma unroll
        for (int cj = 0; cj < 2; ++cj) {
            if (!nok[cj]) continue;
            #pragma unroll
            for (int r = 0; r < 16; ++r) {
                int v = vbase + (r & 3) + 8 * (r >> 2);
                if (v < V_) {
                    float val = acc[ri][cj][r] * INV24 + biasv[cj];
                    cw[(size_t)v * CWS + ncol[cj]] = fmaxf(logsigf_fast(val), lwv[cj]);
                }
            }
        }
    }
}

// ---------------- f32 fallback (round-2 kernel) ----------------

__global__ __launch_bounds__(256) void k1_gemm_cw(
    const float* __restrict__ emb,
    const float* __restrict__ diags,
    const float* __restrict__ bias,
    const float* __restrict__ wildc,
    float* __restrict__ cw)
{
    __shared__ float As[BK][LDP];
    __shared__ float Bs[BK][LDP];

    const int tid = threadIdx.x;
    const int v0 = blockIdx.x * BM;
    const int n0 = blockIdx.y * BN;
    const int tx = tid & 15;
    const int ty = tid >> 4;

    float acc[8][8];
    #pragma unroll
    for (int i = 0; i < 8; ++i)
        #pragma unroll
        for (int j = 0; j < 8; ++j) acc[i][j] = 0.f;

    const int a_k = tid >> 4;
    const int a_v = (tid & 15) * 8;
    const int b_n   = tid >> 1;
    const int b_kof = (tid & 1) * 8;

    int  brow;
    bool bval;
    {
        int n = n0 + b_n;
        bval = (n < NOUT);
        brow = bval ? ((n / 5) * 6 + (n % 5)) : 0;
    }

    for (int k0 = 0; k0 < KDIM; k0 += BK) {
        {
            float4 f0 = {0,0,0,0}, f1 = {0,0,0,0};
            int k = k0 + a_k;
            if (k < KDIM) {
                const float* src = emb + (size_t)k * V_ + v0 + a_v;
                if (v0 + a_v + 3 < V_) f0 = *(const float4*)src;
                if (v0 + a_v + 7 < V_) f1 = *(const float4*)(src + 4);
            }
            *(float4*)&As[a_k][a_v]     = f0;
            *(float4*)&As[a_k][a_v + 4] = f1;
        }
        {
            float4 f = {0,0,0,0}, g = {0,0,0,0};
            if (bval) {
                const float* src = diags + (size_t)brow * KDIM + k0 + b_kof;
                if (k0 + b_kof + 3 < KDIM) f = *(const float4*)src;
                if (k0 + b_kof + 7 < KDIM) g = *(const float4*)(src + 4);
            }
            Bs[b_kof + 0][b_n] = f.x;
            Bs[b_kof + 1][b_n] = f.y;
            Bs[b_kof + 2][b_n] = f.z;
            Bs[b_kof + 3][b_n] = f.w;
            Bs[b_kof + 4][b_n] = g.x;
            Bs[b_kof + 5][b_n] = g.y;
            Bs[b_kof + 6][b_n] = g.z;
            Bs[b_kof + 7][b_n] = g.w;
        }
        __syncthreads();
        #pragma unroll
        for (int k = 0; k < BK; ++k) {
            float4 a0 = *(const float4*)&As[k][tx * 4];
            float4 a1 = *(const float4*)&As[k][64 + tx * 4];
            float4 b0 = *(const float4*)&Bs[k][ty * 8];
            float4 b1 = *(const float4*)&Bs[k][ty * 8 + 4];
            float av[8] = {a0.x, a0.y, a0.z, a0.w, a1.x, a1.y, a1.z, a1.w};
            float bv[8] = {b0.x, b0.y, b0.z, b0.w, b1.x, b1.y, b1.z, b1.w};
            #pragma unroll
            for (int i = 0; i < 8; ++i)
                #pragma unroll
                for (int j = 0; j < 8; ++j)
                    acc[i][j] = fmaf(av[i], bv[j], acc[i][j]);
        }
        __syncthreads();
    }

    float biasv[8], lwv[8];
    #pragma unroll
    for (int j = 0; j < 8; ++j) {
        int n  = n0 + ty * 8 + j;
        int nc = (n < NOUT) ? n : 0;
        int pm = (nc / 5) * 6 + (nc % 5);
        biasv[j] = bias[pm];
        lwv[j]   = logsigf(wildc[nc]);
    }
    #pragma unroll
    for (int i = 0; i < 8; ++i) {
        int v = v0 + ((i < 4) ? (tx * 4 + i) : (64 + tx * 4 + (i - 4)));
        if (v >= V_) continue;
        float r[8];
        #pragma unroll
        for (int j = 0; j < 8; ++j)
            r[j] = fmaxf(logsigf(acc[i][j] + biasv[j]), lwv[j]);
        float* dst = cw + (size_t)v * CWS + n0 + ty * 8;
        if (n0 + ty * 8     < NOUT) *(float4*)dst       = make_float4(r[0], r[1], r[2], r[3]);
        if (n0 + ty * 8 + 4 < NOUT) *(float4*)(dst + 4) = make_float4(r[4], r[5], r[6], r[7]);
    }
}

// ---------------- scan (cooperative LDS staging) + finalize ----------------

__global__ __launch_bounds__(192) void k2_scan(
    const int* __restrict__ docs,
    const int* __restrict__ doc_lens,
    const float* __restrict__ cw,
    float* __restrict__ cs)
{
    const int ci = blockIdx.x;
    const int b  = blockIdx.y;
    const int t0 = ci * TCHUNK;
    const int ts = (t0 >= WARM) ? (t0 - WARM) : 0;
    const int dl = doc_lens[b];
    const int te = min(t0 + TCHUNK, dl);
    const int nt = te - ts;              // tokens to process (may be <= 0)

    __shared__ int   toks[TCHUNK + WARM];
    __shared__ float rows[3][768];       // 3 KB rows (750 used + pad)

    const int t    = threadIdx.x;
    const int lane = t & 63;
    const int w    = t >> 6;             // wave 0..2

    if (t < TCHUNK + WARM) {
        int tt = ts + t;
        toks[t] = docs[b * L_ + min(tt, L_ - 1)];
    }
    __syncthreads();

    const int p      = t;                // pattern if < P_
    const int e      = (p < 50) ? 3 : (p < 100) ? 4 : 5;
    const int warm_n = t0 - ts;
    float h1 = NEGF, h2 = NEGF, h3 = NEGF, h4 = NEGF, h5 = NEGF, sc = NEGF;

    const int nrounds = (nt > 0) ? (nt + 2) / 3 : 0;
    for (int r = 0; r < nrounds; ++r) {
        {
            int idx = min(3 * r + w, nt - 1);
            const char* rowp = (const char*)(cw + (size_t)toks[idx] * CWS);
            char* lbase = (char*)&rows[w][0];
            #pragma unroll
            for (int jj = 0; jj < 3; ++jj)
                gload_lds16(rowp + jj * 1024 + lane * 16,
                            lbase + jj * 1024 + lane * 16);
        }
        __syncthreads();                 // DMA complete, rows readable

        #pragma unroll
        for (int u = 0; u < 3; ++u) {
            int i2 = 3 * r + u;
            if (i2 >= nt) break;
            if (p < P_) {
                const float* rp = &rows[u][p * 5];
                float c0 = rp[0], c1 = rp[1], c2 = rp[2], c3 = rp[3], c4 = rp[4];
                h5 = h4 + c4;
                h4 = h3 + c3;
                h3 = h2 + c2;
                h2 = h1 + c1;
                h1 = c0;                 // h0 = 0 always
                if (i2 >= warm_n) {
                    float esv = (e == 3) ? h3 : (e == 4) ? h4 : h5;
                    sc = fmaxf(sc, esv);
                }
            }
        }
        __syncthreads();                 // protect rows before next DMA round
    }
    if (p < P_) cs[(size_t)(b * NCHUNK + ci) * CS_STRIDE + p] = sc;
}

__device__ __forceinline__ float block_sum192(float v, volatile float* red, int tid) {
    #pragma unroll
    for (int off = 32; off > 0; off >>= 1) v += __shfl_down(v, off, 64);
    __syncthreads();
    if ((tid & 63) == 0) red[tid >> 6] = v;
    __syncthreads();
    return red[0] + red[1] + red[2];
}

__global__ __launch_bounds__(192) void k3_final(
    const float* __restrict__ cs,
    const float* __restrict__ gamma,
    const float* __restrict__ beta,
    const float* __restrict__ lw,
    const float* __restrict__ lb,
    float* __restrict__ out)
{
    __shared__ float red[3];
    const int b   = blockIdx.x;
    const int tid = threadIdx.x;
    float s = 0.f;
    if (tid < P_) {
        float m = NEGF;
        const float* row = cs + (size_t)b * NCHUNK * CS_STRIDE + tid;
        #pragma unroll
        for (int ci = 0; ci < NCHUNK; ++ci) m = fmaxf(m, row[ci * CS_STRIDE]);
        s = expf(m);
    }
    float mu = block_sum192(s, red, tid) * (1.f / P_);
    float d  = (tid < P_) ? (s - mu) : 0.f;
    float var = block_sum192(d * d, red, tid) * (1.f / P_);
    float bin = 0.f;
    if (tid < P_) {
        float norm = (s - mu) * rsqrtf(var + 1e-5f) * gamma[tid] + beta[tid];
        bin = (norm > 0.f) ? 1.f : 0.f;
    }
    float o0 = block_sum192((tid < P_) ? bin * lw[tid]      : 0.f, red, tid);
    float o1 = block_sum192((tid < P_) ? bin * lw[P_ + tid] : 0.f, red, tid);
    if (tid == 0) {
        out[b * 2 + 0] = o0 + lb[0];
        out[b * 2 + 1] = o1 + lb[1];
    }
}

extern "C" void kernel_launch(void* const* d_in, const int* in_sizes, int n_in,
                              void* d_out, int out_size, void* d_ws, size_t ws_size,
                              hipStream_t stream)
{
    const int*   docs  = (const int*)  d_in[0];
    const int*   dlens = (const int*)  d_in[1];
    const float* emb   = (const float*)d_in[2];
    const float* diags = (const float*)d_in[3];
    const float* bias  = (const float*)d_in[4];
    const float* wildc = (const float*)d_in[5];
    const float* gamma = (const float*)d_in[6];
    const float* beta  = (const float*)d_in[7];
    const float* lw    = (const float*)d_in[8];
    const float* lb    = (const float*)d_in[9];
    float* out = (float*)d_out;

    // ws layout: cw | cs | a_t | b_t
    const size_t cw_b = (size_t)V_ * CWS * 4;                 // 60,160,000
    const size_t cs_b = (size_t)B_ * NCHUNK * CS_STRIDE * 4;  // 655,360
    const size_t at_b = (size_t)NVG * NIT * TILE_U4 * 16;     // 25,722,880
    const size_t bt_b = (size_t)NJ  * NIT * TILE_U4 * 16;     // 983,040
    const size_t need = cw_b + cs_b + at_b + bt_b;

    char* base = (char*)d_ws;
    float* cw = (float*)base;
    float* cs = (float*)(base + cw_b);
    uint4* at = (uint4*)(base + cw_b + cs_b);
    uint4* bt = (uint4*)(base + cw_b + cs_b + at_b);

    if (ws_size >= need) {
        p12_split<<<NVG * 5 + NJ * NIT, 256, 0, stream>>>(emb, diags, at, bt);
        // 1-D grid, XCD-colocated siblings: 160 v-group slots x 6 n-groups = 960
        k1m_gemm<<<960, 256, 0, stream>>>(at, bt, bias, wildc, cw);
    } else {
        dim3 g1((V_ + BM - 1) / BM, (NOUT + BN - 1) / BN);
        k1_gemm_cw<<<g1, 256, 0, stream>>>(emb, diags, bias, wildc, cw);
    }

    dim3 g2(NCHUNK, B_);
    k2_scan<<<g2, 192, 0, stream>>>(docs, dlens, cw, cs);
    k3_final<<<B_, 192, 0, stream>>>(cs, gamma, beta, lw, lb, out);
}